// Round 4
// baseline (476.601 us; speedup 1.0000x reference)
//
#include <hip/hip_runtime.h>

#define TSEQ 4096
#define CEMB 768
#define NHEAD 12

using bf16x8 = __attribute__((ext_vector_type(8))) short;
using f32x4  = __attribute__((ext_vector_type(4))) float;

__device__ __forceinline__ unsigned int f2bf(float f) {
    unsigned int u = __float_as_uint(f);
    return (u + 0x7fffu + ((u >> 16) & 1u)) >> 16;   // RNE
}
__device__ __forceinline__ void async_cp16(void* lds, const void* g) {
    __builtin_amdgcn_global_load_lds(
        (const __attribute__((address_space(1))) void*)g,
        (__attribute__((address_space(3))) void*)lds, 16, 0, 0);
}

// ---------------- x fp32 -> bf16 ----------------
__global__ __launch_bounds__(256) void cvt_bf16(
    const float* __restrict__ X, unsigned short* __restrict__ Xb, int n8)
{
    int i = blockIdx.x * 256 + threadIdx.x;
    if (i >= n8) return;
    float4 a = *reinterpret_cast<const float4*>(&X[(size_t)i * 8]);
    float4 b = *reinterpret_cast<const float4*>(&X[(size_t)i * 8 + 4]);
    uint4 o;
    o.x = f2bf(a.x) | (f2bf(a.y) << 16);
    o.y = f2bf(a.z) | (f2bf(a.w) << 16);
    o.z = f2bf(b.x) | (f2bf(b.y) << 16);
    o.w = f2bf(b.z) | (f2bf(b.w) << 16);
    *reinterpret_cast<uint4*>(&Xb[(size_t)i * 8]) = o;
}

// ---------------- W fp32 [K][N] -> bf16 [N][K] ----------------
__global__ __launch_bounds__(256) void wtrans(
    const float* __restrict__ W, unsigned short* __restrict__ WT, int K, int N)
{
    __shared__ unsigned short tile[64][72];
    const int k0 = blockIdx.y * 64, n0 = blockIdx.x * 64;
    const int tid = threadIdx.x;
#pragma unroll
    for (int it = 0; it < 4; ++it) {
        int f = tid + it * 256;
        int r = f >> 4, c4 = f & 15;
        float4 v = *reinterpret_cast<const float4*>(&W[(size_t)(k0 + r) * N + n0 + c4 * 4]);
        tile[r][c4 * 4 + 0] = (unsigned short)f2bf(v.x);
        tile[r][c4 * 4 + 1] = (unsigned short)f2bf(v.y);
        tile[r][c4 * 4 + 2] = (unsigned short)f2bf(v.z);
        tile[r][c4 * 4 + 3] = (unsigned short)f2bf(v.w);
    }
    __syncthreads();
#pragma unroll
    for (int it = 0; it < 2; ++it) {
        int f = tid + it * 256;
        int rn = f >> 3, c8 = f & 7;
        unsigned short tmp[8];
#pragma unroll
        for (int j = 0; j < 8; ++j) tmp[j] = tile[c8 * 8 + j][rn];
        *reinterpret_cast<uint4*>(&WT[(size_t)(n0 + rn) * K + k0 + c8 * 8]) =
            *reinterpret_cast<uint4*>(tmp);
    }
}

// ---------------- bf16 MFMA GEMM: C[m][n] = A[m][k] * BT[n][k] + bias ----------------
template<int BF16OUT, int QSCALE>
__global__ __launch_bounds__(256) void gemm_mfma(
    const unsigned short* __restrict__ A,
    const unsigned short* __restrict__ BT,
    const float* __restrict__ bias,
    void* __restrict__ Cv,
    int M, int N, int K)
{
    __shared__ __align__(16) unsigned short As[128 * 64];
    __shared__ __align__(16) unsigned short Bs[128 * 64];

    const int nwg = gridDim.x * gridDim.y;
    const int id = blockIdx.y * gridDim.x + blockIdx.x;
    const int qx = nwg >> 3;
    const int swz = (id & 7) * qx + (id >> 3);
    const int nb = N >> 7;
    const int m0 = (swz / nb) * 128, n0 = (swz % nb) * 128;

    const int tid = threadIdx.x;
    const int w = tid >> 6, lane = tid & 63;
    const int wr = w >> 1, wc = w & 1;
    const int lq = lane & 15, g = lane >> 4;
    const int wrOff = wr * 64, wcOff = wc * 64;

    f32x4 acc[4][4];
#pragma unroll
    for (int i = 0; i < 4; ++i)
#pragma unroll
        for (int j = 0; j < 4; ++j) acc[i][j] = (f32x4){0.f, 0.f, 0.f, 0.f};

    for (int k0 = 0; k0 < K; k0 += 64) {
#pragma unroll
        for (int it = 0; it < 4; ++it) {
            const int dbase = it * 256 + w * 64;
            const int d = dbase + lane;
            const int r = d >> 3;
            const int s = (d & 7) ^ (r & 7);
            async_cp16((char*)As + dbase * 16, A + (size_t)(m0 + r) * K + k0 + s * 8);
            async_cp16((char*)Bs + dbase * 16, BT + (size_t)(n0 + r) * K + k0 + s * 8);
        }
        __syncthreads();

#pragma unroll
        for (int kk = 0; kk < 2; ++kk) {
            bf16x8 af[4], bfr[4];
#pragma unroll
            for (int i = 0; i < 4; ++i) {
                const int ra = wrOff + i * 16 + lq;
                af[i] = *reinterpret_cast<const bf16x8*>(
                    (char*)As + ra * 128 + (((kk * 4 + g) ^ (ra & 7)) << 4));
                const int rb = wcOff + i * 16 + lq;
                bfr[i] = *reinterpret_cast<const bf16x8*>(
                    (char*)Bs + rb * 128 + (((kk * 4 + g) ^ (rb & 7)) << 4));
            }
#pragma unroll
            for (int i = 0; i < 4; ++i)
#pragma unroll
                for (int j = 0; j < 4; ++j)
                    acc[i][j] = __builtin_amdgcn_mfma_f32_16x16x32_bf16(
                        af[i], bfr[j], acc[i][j], 0, 0, 0);
        }
        __syncthreads();
    }

#pragma unroll
    for (int i = 0; i < 4; ++i)
#pragma unroll
        for (int j = 0; j < 4; ++j) {
            const int col = n0 + wcOff + j * 16 + lq;
            const float bv = bias[col];
            const float scl = (QSCALE && col < CEMB) ? 0.125f : 1.0f;
#pragma unroll
            for (int rg = 0; rg < 4; ++rg) {
                const int row = m0 + wrOff + i * 16 + g * 4 + rg;
                const float v = (acc[i][j][rg] + bv) * scl;
                if (BF16OUT)
                    ((unsigned short*)Cv)[(size_t)row * N + col] = (unsigned short)f2bf(v);
                else
                    ((float*)Cv)[(size_t)row * N + col] = v;
            }
        }
}

// ---------------- V transpose: qkv bf16 v-slice -> Vt [bh][64 d][4096 t] ----------------
__global__ __launch_bounds__(256) void vtrans(
    const unsigned short* __restrict__ qkvB, unsigned short* __restrict__ VtG)
{
    __shared__ unsigned short tile[64][66];
    const int t0 = blockIdx.x * 64;
    const int bh = blockIdx.y;
    const int b = bh / NHEAD, h = bh % NHEAD;
    const size_t rowBase = (size_t)b * TSEQ;
    const int tid = threadIdx.x;

#pragma unroll
    for (int it = 0; it < 2; ++it) {
        int f = tid + 256 * it;
        int r = f >> 3, s = f & 7;
        unsigned short tmp[8];
        *reinterpret_cast<uint4*>(tmp) = *reinterpret_cast<const uint4*>(
            &qkvB[(rowBase + t0 + r) * 2304 + 2 * CEMB + h * 64 + s * 8]);
#pragma unroll
        for (int j = 0; j < 8; ++j) tile[r][s * 8 + j] = tmp[j];
    }
    __syncthreads();
#pragma unroll
    for (int it = 0; it < 2; ++it) {
        int f = tid + 256 * it;
        int d = f >> 3, c = f & 7;
        unsigned short tmp[8];
#pragma unroll
        for (int j = 0; j < 8; ++j) tmp[j] = tile[c * 8 + j][d];
        *reinterpret_cast<uint4*>(&VtG[(size_t)bh * 64 * TSEQ + (size_t)d * TSEQ + t0 + c * 8]) =
            *reinterpret_cast<uint4*>(tmp);
    }
}

// ---------------- MFMA flash attention v2 ----------------
// Swapped-operand QK^T (q lane-local), reg-resident P, reg-staged KV prefetch.
// grid (T/64, B*H), block 256 = 4 waves; wave w owns q rows 16w..16w+15.
__global__ __launch_bounds__(256) void attn_mfma2(
    const unsigned short* __restrict__ qkvB,   // bf16 [8192][2304], q pre-scaled 1/8
    const unsigned short* __restrict__ VtG,    // bf16 [24][64][4096]
    unsigned short* __restrict__ Yb)           // bf16 [8192][768]
{
    __shared__ __align__(16) char Kl[16384];   // [kv 128][d 64], 16B-chunk XOR swizzle
    __shared__ __align__(16) char Vl[16384];   // [d 64][kv 128], 16B-chunk XOR swizzle

    const int qt = gridDim.x - 1 - blockIdx.x;   // heavy tiles first
    const int bh = blockIdx.y;
    const int b = bh / NHEAD, h = bh % NHEAD;
    const int tid = threadIdx.x;
    const int w = tid >> 6, lane = tid & 63;
    const int g = lane >> 4, lq = lane & 15;

    const size_t rowBase = (size_t)b * TSEQ;
    const int kOff = CEMB + h * 64;
    const unsigned short* Vhead = VtG + (size_t)bh * 64 * TSEQ;

    // Q fragment: lane holds Q[16w+lq][32dt+8g+j]  (B-operand of swapped QK^T)
    bf16x8 qf[2];
    {
        const size_t qrow = rowBase + (size_t)qt * 64 + 16 * w + lq;
#pragma unroll
        for (int dt = 0; dt < 2; ++dt)
            qf[dt] = *reinterpret_cast<const bf16x8*>(
                &qkvB[qrow * 2304 + h * 64 + 32 * dt + 8 * g]);
    }
    const int q_loc = qt * 64 + 16 * w + lq;     // this lane's q row (batch-local)

    f32x4 ofr[4];                                 // O^T[d=16dt+4g+reg][q=lq]
#pragma unroll
    for (int dt = 0; dt < 4; ++dt) ofr[dt] = (f32x4){0.f, 0.f, 0.f, 0.f};
    float m = -1e30f, l = 0.f;

    const int nkt = (qt >> 1) + 1;               // 128-wide kv tiles

    // ---- reg-staged prefetch buffers ----
    uint4 kreg[4], vreg[4];
#pragma unroll
    for (int it = 0; it < 4; ++it) {
        const int idx = it * 256 + tid;
        const int kv = idx >> 3, s = idx & 7;
        kreg[it] = *reinterpret_cast<const uint4*>(
            &qkvB[(rowBase + kv) * 2304 + kOff + s * 8]);
        const int d = idx >> 4, s2 = idx & 15;
        vreg[it] = *reinterpret_cast<const uint4*>(&Vhead[(size_t)d * TSEQ + s2 * 8]);
    }

    for (int kt = 0; kt < nkt; ++kt) {
        if (kt) __syncthreads();
        // regs -> LDS (swizzled)
#pragma unroll
        for (int it = 0; it < 4; ++it) {
            const int idx = it * 256 + tid;
            const int kv = idx >> 3, s = idx & 7;
            *reinterpret_cast<uint4*>(Kl + kv * 128 + ((s ^ (kv & 7)) << 4)) = kreg[it];
            const int d = idx >> 4, s2 = idx & 15;
            *reinterpret_cast<uint4*>(Vl + d * 256 + ((s2 ^ (d & 15)) << 4)) = vreg[it];
        }
        __syncthreads();

        // prefetch next tile (latency hides under compute below)
        if (kt + 1 < nkt) {
            const int kt0n = (kt + 1) * 128;
#pragma unroll
            for (int it = 0; it < 4; ++it) {
                const int idx = it * 256 + tid;
                const int kv = idx >> 3, s = idx & 7;
                kreg[it] = *reinterpret_cast<const uint4*>(
                    &qkvB[(rowBase + kt0n + kv) * 2304 + kOff + s * 8]);
                const int d = idx >> 4, s2 = idx & 15;
                vreg[it] = *reinterpret_cast<const uint4*>(
                    &Vhead[(size_t)d * TSEQ + kt0n + s2 * 8]);
            }
        }

        // ---- S^T = mfma(K, Q): sfr[c][r] = P(q=lq, kv=16c+4g+r) ----
        f32x4 sfr[8];
#pragma unroll
        for (int c = 0; c < 8; ++c) {
            const int krow = 16 * c + lq;
            const int xr = lq & 7;
            bf16x8 kf0 = *reinterpret_cast<const bf16x8*>(Kl + krow * 128 + ((g ^ xr) << 4));
            bf16x8 kf1 = *reinterpret_cast<const bf16x8*>(Kl + krow * 128 + (((4 + g) ^ xr) << 4));
            f32x4 a = (f32x4){0.f, 0.f, 0.f, 0.f};
            a = __builtin_amdgcn_mfma_f32_16x16x32_bf16(kf0, qf[0], a, 0, 0, 0);
            a = __builtin_amdgcn_mfma_f32_16x16x32_bf16(kf1, qf[1], a, 0, 0, 0);
            sfr[c] = a;
        }

        // causal mask (only the last kv tile straddles the diagonal)
        if (kt == nkt - 1) {
            const int kvb = kt * 128 + 4 * g;
#pragma unroll
            for (int c = 0; c < 8; ++c)
#pragma unroll
                for (int r = 0; r < 4; ++r)
                    if (kvb + 16 * c + r > q_loc) sfr[c][r] = -1e30f;
        }

        // ---- online softmax: row q=lq is spread over the 4 g-replica lanes ----
        float mx = sfr[0][0];
#pragma unroll
        for (int c = 0; c < 8; ++c)
#pragma unroll
            for (int r = 0; r < 4; ++r) mx = fmaxf(mx, sfr[c][r]);
        mx = fmaxf(mx, __shfl_xor(mx, 16));
        mx = fmaxf(mx, __shfl_xor(mx, 32));
        const float mnew = fmaxf(m, mx);
        const float al = __expf(m - mnew);
        float rs = 0.f;
#pragma unroll
        for (int c = 0; c < 8; ++c)
#pragma unroll
            for (int r = 0; r < 4; ++r) {
                const float p = __expf(sfr[c][r] - mnew);
                sfr[c][r] = p;
                rs += p;
            }
        rs += __shfl_xor(rs, 16);
        rs += __shfl_xor(rs, 32);
        l = al * l + rs;
        m = mnew;
#pragma unroll
        for (int dt = 0; dt < 4; ++dt) ofr[dt] *= al;

        // ---- O^T += V^T P^T : zero-padded K=32 MFMAs, P straight from regs ----
#pragma unroll
        for (int c = 0; c < 8; ++c) {
            uint4 pw;
            pw.x = f2bf(sfr[c][0]) | (f2bf(sfr[c][1]) << 16);
            pw.y = f2bf(sfr[c][2]) | (f2bf(sfr[c][3]) << 16);
            pw.z = 0; pw.w = 0;
            const bf16x8 pf = __builtin_bit_cast(bf16x8, pw);
            const int chunk = 2 * c + (g >> 1);
            const int half = (g & 1) * 8;
#pragma unroll
            for (int dt = 0; dt < 4; ++dt) {
                const int drow = 16 * dt + lq;
                uint2 av = *reinterpret_cast<const uint2*>(
                    Vl + drow * 256 + ((chunk ^ lq) << 4) + half);
                uint4 aw; aw.x = av.x; aw.y = av.y; aw.z = 0; aw.w = 0;
                const bf16x8 af = __builtin_bit_cast(bf16x8, aw);
                ofr[dt] = __builtin_amdgcn_mfma_f32_16x16x32_bf16(af, pf, ofr[dt], 0, 0, 0);
            }
        }
    }

    // ---- normalize + packed 8B stores (d contiguous per lane) ----
    const float inv = 1.f / l;
    const size_t orow = rowBase + (size_t)qt * 64 + 16 * w + lq;
#pragma unroll
    for (int dt = 0; dt < 4; ++dt) {
        uint2 o;
        o.x = f2bf(ofr[dt][0] * inv) | (f2bf(ofr[dt][1] * inv) << 16);
        o.y = f2bf(ofr[dt][2] * inv) | (f2bf(ofr[dt][3] * inv) << 16);
        *reinterpret_cast<uint2*>(&Yb[orow * CEMB + h * 64 + 16 * dt + 4 * g]) = o;
    }
}

extern "C" void kernel_launch(void* const* d_in, const int* in_sizes, int n_in,
                              void* d_out, int out_size, void* d_ws, size_t ws_size,
                              hipStream_t stream)
{
    const float* x      = (const float*)d_in[0];
    const float* w_attn = (const float*)d_in[1];
    const float* b_attn = (const float*)d_in[2];
    const float* w_proj = (const float*)d_in[3];
    const float* b_proj = (const float*)d_in[4];
    float* out = (float*)d_out;

    const int M = 2 * TSEQ;  // 8192
    char* ws = (char*)d_ws;
    unsigned short* qkvB = (unsigned short*)ws;                   // 37,748,736 B
    unsigned short* VtG  = (unsigned short*)(ws + 37748736);      // 12,582,912 B
    unsigned short* xYb  = (unsigned short*)(ws + 50331648);      // 12,582,912 B (xB, then Yb)
    unsigned short* wT   = (unsigned short*)(ws + 62914560);      //  3,538,944 B
    unsigned short* wpT  = (unsigned short*)(ws + 66453504);      //  1,179,648 B

    cvt_bf16<<<dim3((M * CEMB) / 8 / 256), 256, 0, stream>>>(x, xYb, (M * CEMB) / 8);
    wtrans<<<dim3(3 * CEMB / 64, CEMB / 64), 256, 0, stream>>>(w_attn, wT, CEMB, 3 * CEMB);
    wtrans<<<dim3(CEMB / 64, CEMB / 64), 256, 0, stream>>>(w_proj, wpT, CEMB, CEMB);

    gemm_mfma<1, 1><<<dim3(3 * CEMB / 128, M / 128), 256, 0, stream>>>(
        xYb, wT, b_attn, qkvB, M, 3 * CEMB, CEMB);

    vtrans<<<dim3(TSEQ / 64, 2 * NHEAD), 256, 0, stream>>>(qkvB, VtG);

    attn_mfma2<<<dim3(TSEQ / 64, 2 * NHEAD), 256, 0, stream>>>(qkvB, VtG, xYb);

    gemm_mfma<0, 0><<<dim3(CEMB / 128, M / 128), 256, 0, stream>>>(
        xYb, wpT, b_proj, out, M, CEMB, CEMB);
}

// Round 5
// 328.390 us; speedup vs baseline: 1.4513x; 1.4513x over previous
//
#include <hip/hip_runtime.h>

#define TSEQ 4096
#define CEMB 768
#define NHEAD 12

using bf16x8 = __attribute__((ext_vector_type(8))) short;
using f32x4  = __attribute__((ext_vector_type(4))) float;

__device__ __forceinline__ unsigned int f2bf(float f) {
    unsigned int u = __float_as_uint(f);
    return (u + 0x7fffu + ((u >> 16) & 1u)) >> 16;   // RNE
}
__device__ __forceinline__ void async_cp16(void* lds, const void* g) {
    __builtin_amdgcn_global_load_lds(
        (const __attribute__((address_space(1))) void*)g,
        (__attribute__((address_space(3))) void*)lds, 16, 0, 0);
}
__device__ __forceinline__ float warp_max16(float v) {
    v = fmaxf(v, __shfl_xor(v, 1));
    v = fmaxf(v, __shfl_xor(v, 2));
    v = fmaxf(v, __shfl_xor(v, 4));
    v = fmaxf(v, __shfl_xor(v, 8));
    return v;
}
__device__ __forceinline__ float warp_sum16(float v) {
    v += __shfl_xor(v, 1);
    v += __shfl_xor(v, 2);
    v += __shfl_xor(v, 4);
    v += __shfl_xor(v, 8);
    return v;
}

// ---------------- x fp32 -> bf16 ----------------
__global__ __launch_bounds__(256) void cvt_bf16(
    const float* __restrict__ X, unsigned short* __restrict__ Xb, int n8)
{
    int i = blockIdx.x * 256 + threadIdx.x;
    if (i >= n8) return;
    float4 a = *reinterpret_cast<const float4*>(&X[(size_t)i * 8]);
    float4 b = *reinterpret_cast<const float4*>(&X[(size_t)i * 8 + 4]);
    uint4 o;
    o.x = f2bf(a.x) | (f2bf(a.y) << 16);
    o.y = f2bf(a.z) | (f2bf(a.w) << 16);
    o.z = f2bf(b.x) | (f2bf(b.y) << 16);
    o.w = f2bf(b.z) | (f2bf(b.w) << 16);
    *reinterpret_cast<uint4*>(&Xb[(size_t)i * 8]) = o;
}

// ---------------- W fp32 [K][N] -> bf16 [N][K] ----------------
__global__ __launch_bounds__(256) void wtrans(
    const float* __restrict__ W, unsigned short* __restrict__ WT, int K, int N)
{
    __shared__ unsigned short tile[64][72];
    const int k0 = blockIdx.y * 64, n0 = blockIdx.x * 64;
    const int tid = threadIdx.x;
#pragma unroll
    for (int it = 0; it < 4; ++it) {
        int f = tid + it * 256;
        int r = f >> 4, c4 = f & 15;
        float4 v = *reinterpret_cast<const float4*>(&W[(size_t)(k0 + r) * N + n0 + c4 * 4]);
        tile[r][c4 * 4 + 0] = (unsigned short)f2bf(v.x);
        tile[r][c4 * 4 + 1] = (unsigned short)f2bf(v.y);
        tile[r][c4 * 4 + 2] = (unsigned short)f2bf(v.z);
        tile[r][c4 * 4 + 3] = (unsigned short)f2bf(v.w);
    }
    __syncthreads();
#pragma unroll
    for (int it = 0; it < 2; ++it) {
        int f = tid + it * 256;
        int rn = f >> 3, c8 = f & 7;
        unsigned short tmp[8];
#pragma unroll
        for (int j = 0; j < 8; ++j) tmp[j] = tile[c8 * 8 + j][rn];
        *reinterpret_cast<uint4*>(&WT[(size_t)(n0 + rn) * K + k0 + c8 * 8]) =
            *reinterpret_cast<uint4*>(tmp);
    }
}

// ---------------- bf16 MFMA GEMM: C[m][n] = A[m][k] * BT[n][k] + bias ----------------
template<int BF16OUT, int QSCALE>
__global__ __launch_bounds__(256) void gemm_mfma(
    const unsigned short* __restrict__ A,
    const unsigned short* __restrict__ BT,
    const float* __restrict__ bias,
    void* __restrict__ Cv,
    int M, int N, int K)
{
    __shared__ __align__(16) unsigned short As[128 * 64];
    __shared__ __align__(16) unsigned short Bs[128 * 64];

    const int nwg = gridDim.x * gridDim.y;
    const int id = blockIdx.y * gridDim.x + blockIdx.x;
    const int qx = nwg >> 3;
    const int swz = (id & 7) * qx + (id >> 3);
    const int nb = N >> 7;
    const int m0 = (swz / nb) * 128, n0 = (swz % nb) * 128;

    const int tid = threadIdx.x;
    const int w = tid >> 6, lane = tid & 63;
    const int wr = w >> 1, wc = w & 1;
    const int lq = lane & 15, g = lane >> 4;
    const int wrOff = wr * 64, wcOff = wc * 64;

    f32x4 acc[4][4];
#pragma unroll
    for (int i = 0; i < 4; ++i)
#pragma unroll
        for (int j = 0; j < 4; ++j) acc[i][j] = (f32x4){0.f, 0.f, 0.f, 0.f};

    for (int k0 = 0; k0 < K; k0 += 64) {
#pragma unroll
        for (int it = 0; it < 4; ++it) {
            const int dbase = it * 256 + w * 64;
            const int d = dbase + lane;
            const int r = d >> 3;
            const int s = (d & 7) ^ (r & 7);
            async_cp16((char*)As + dbase * 16, A + (size_t)(m0 + r) * K + k0 + s * 8);
            async_cp16((char*)Bs + dbase * 16, BT + (size_t)(n0 + r) * K + k0 + s * 8);
        }
        __syncthreads();

#pragma unroll
        for (int kk = 0; kk < 2; ++kk) {
            bf16x8 af[4], bfr[4];
#pragma unroll
            for (int i = 0; i < 4; ++i) {
                const int ra = wrOff + i * 16 + lq;
                af[i] = *reinterpret_cast<const bf16x8*>(
                    (char*)As + ra * 128 + (((kk * 4 + g) ^ (ra & 7)) << 4));
                const int rb = wcOff + i * 16 + lq;
                bfr[i] = *reinterpret_cast<const bf16x8*>(
                    (char*)Bs + rb * 128 + (((kk * 4 + g) ^ (rb & 7)) << 4));
            }
#pragma unroll
            for (int i = 0; i < 4; ++i)
#pragma unroll
                for (int j = 0; j < 4; ++j)
                    acc[i][j] = __builtin_amdgcn_mfma_f32_16x16x32_bf16(
                        af[i], bfr[j], acc[i][j], 0, 0, 0);
        }
        __syncthreads();
    }

#pragma unroll
    for (int i = 0; i < 4; ++i)
#pragma unroll
        for (int j = 0; j < 4; ++j) {
            const int col = n0 + wcOff + j * 16 + lq;
            const float bv = bias[col];
            const float scl = (QSCALE && col < CEMB) ? 0.125f : 1.0f;
#pragma unroll
            for (int rg = 0; rg < 4; ++rg) {
                const int row = m0 + wrOff + i * 16 + g * 4 + rg;
                const float v = (acc[i][j][rg] + bv) * scl;
                if (BF16OUT)
                    ((unsigned short*)Cv)[(size_t)row * N + col] = (unsigned short)f2bf(v);
                else
                    ((float*)Cv)[(size_t)row * N + col] = v;
            }
        }
}

// ---------------- V transpose: qkv bf16 v-slice -> Vt [bh][64 d][4096 t] ----------------
__global__ __launch_bounds__(256) void vtrans(
    const unsigned short* __restrict__ qkvB, unsigned short* __restrict__ VtG)
{
    __shared__ unsigned short tile[64][66];
    const int t0 = blockIdx.x * 64;
    const int bh = blockIdx.y;
    const int b = bh / NHEAD, h = bh % NHEAD;
    const size_t rowBase = (size_t)b * TSEQ;
    const int tid = threadIdx.x;

#pragma unroll
    for (int it = 0; it < 2; ++it) {
        int f = tid + 256 * it;
        int r = f >> 3, s = f & 7;
        unsigned short tmp[8];
        *reinterpret_cast<uint4*>(tmp) = *reinterpret_cast<const uint4*>(
            &qkvB[(rowBase + t0 + r) * 2304 + 2 * CEMB + h * 64 + s * 8]);
#pragma unroll
        for (int j = 0; j < 8; ++j) tile[r][s * 8 + j] = tmp[j];
    }
    __syncthreads();
#pragma unroll
    for (int it = 0; it < 2; ++it) {
        int f = tid + 256 * it;
        int d = f >> 3, c = f & 7;
        unsigned short tmp[8];
#pragma unroll
        for (int j = 0; j < 8; ++j) tmp[j] = tile[c * 8 + j][d];
        *reinterpret_cast<uint4*>(&VtG[(size_t)bh * 64 * TSEQ + (size_t)d * TSEQ + t0 + c * 8]) =
            *reinterpret_cast<uint4*>(tmp);
    }
}

// Per-tile compute: identical math to the verified round-3 kernel.
#define PROCESS_TILE(QF, MM, LL, OO, DIAG)                                            \
{                                                                                     \
    f32x4 sfr[4];                                                                     \
    _Pragma("unroll")                                                                 \
    for (int c = 0; c < 4; ++c) {                                                     \
        const int kvr = 16 * c + lq;                                                  \
        const int xr = lq & 7;                                                        \
        bf16x8 k0 = *reinterpret_cast<const bf16x8*>(Kb + kvr * 128 + ((g ^ xr) << 4));       \
        bf16x8 k1 = *reinterpret_cast<const bf16x8*>(Kb + kvr * 128 + (((4 + g) ^ xr) << 4)); \
        f32x4 a0 = (f32x4){0.f, 0.f, 0.f, 0.f};                                       \
        a0 = __builtin_amdgcn_mfma_f32_16x16x32_bf16(QF[0], k0, a0, 0, 0, 0);         \
        a0 = __builtin_amdgcn_mfma_f32_16x16x32_bf16(QF[1], k1, a0, 0, 0, 0);         \
        sfr[c] = a0;                                                                  \
    }                                                                                 \
    if (DIAG) {                                                                       \
        const int qp = 16 * w + 4 * g;                                                \
        _Pragma("unroll")                                                             \
        for (int c = 0; c < 4; ++c) {                                                 \
            const int kp = 16 * c + lq;                                               \
            _Pragma("unroll")                                                         \
            for (int r = 0; r < 4; ++r)                                               \
                if (kp > qp + r) sfr[c][r] = -1e30f;                                  \
        }                                                                             \
    }                                                                                 \
    _Pragma("unroll")                                                                 \
    for (int r = 0; r < 4; ++r) {                                                     \
        float mx = fmaxf(fmaxf(sfr[0][r], sfr[1][r]), fmaxf(sfr[2][r], sfr[3][r]));   \
        mx = warp_max16(mx);                                                          \
        float mnew = fmaxf(MM[r], mx);                                                \
        float al = __expf(MM[r] - mnew);                                              \
        float rs = 0.f;                                                               \
        _Pragma("unroll")                                                             \
        for (int c = 0; c < 4; ++c) {                                                 \
            float p = __expf(sfr[c][r] - mnew);                                       \
            sfr[c][r] = p;                                                            \
            rs += p;                                                                  \
        }                                                                             \
        rs = warp_sum16(rs);                                                          \
        LL[r] = al * LL[r] + rs;                                                      \
        MM[r] = mnew;                                                                 \
        _Pragma("unroll")                                                             \
        for (int dt = 0; dt < 4; ++dt) OO[dt][r] *= al;                               \
    }                                                                                 \
    _Pragma("unroll")                                                                 \
    for (int c = 0; c < 4; ++c) {                                                     \
        const int kp = 16 * c + lq;                                                   \
        _Pragma("unroll")                                                             \
        for (int r = 0; r < 4; ++r) {                                                 \
            const int qp = 4 * g + r;                                                 \
            const int byt = qp * 128 + (((kp >> 3) ^ (qp & 7)) << 4) + (kp & 7) * 2;  \
            *reinterpret_cast<unsigned short*>(Pw + byt) = (unsigned short)f2bf(sfr[c][r]); \
        }                                                                             \
    }                                                                                 \
    _Pragma("unroll")                                                                 \
    for (int ktile = 0; ktile < 2; ++ktile) {                                         \
        bf16x8 pf = *reinterpret_cast<const bf16x8*>(                                 \
            Pw + lq * 128 + (((4 * ktile + g) ^ (lq & 7)) << 4));                     \
        _Pragma("unroll")                                                             \
        for (int dt = 0; dt < 4; ++dt) {                                              \
            const int d = 16 * dt + lq;                                               \
            bf16x8 vf = *reinterpret_cast<const bf16x8*>(                             \
                Vb + d * 128 + (((4 * ktile + g) ^ (d & 7)) << 4));                   \
            OO[dt] = __builtin_amdgcn_mfma_f32_16x16x32_bf16(pf, vf, OO[dt], 0, 0, 0);\
        }                                                                             \
    }                                                                                 \
}

// ---------------- MFMA flash attention v3: balanced q-tile pairs + async dbuf ----------------
// grid (T/128, B*H), block 256 = 4 waves. Block i handles q-tiles i and 63-i (65 steps each).
__global__ __launch_bounds__(256) void attn_mfma3(
    const unsigned short* __restrict__ qkvB,   // bf16 [8192][2304], q pre-scaled 1/8
    const unsigned short* __restrict__ VtG,    // bf16 [24][64][4096]
    unsigned short* __restrict__ Yb)           // bf16 [8192][768]
{
    __shared__ __align__(16) char Kl[2][8192];   // [kv 64][d 64], 16B-chunk XOR swizzle
    __shared__ __align__(16) char Vl[2][8192];   // [d 64][kv 64], swizzled
    __shared__ __align__(16) char Pl[8192];      // 4 waves x [q 16][kv 64], swizzled

    const int NT = TSEQ / 64;                    // 64 q-tiles per bh
    const int qtA = blockIdx.x;                  // 0..31
    const int qtB = NT - 1 - qtA;                // 63..32
    const int bh = blockIdx.y;
    const int b = bh / NHEAD, h = bh % NHEAD;
    const int tid = threadIdx.x;
    const int w = tid >> 6, lane = tid & 63;
    const int g = lane >> 4, lq = lane & 15;

    const size_t rowBase = (size_t)b * TSEQ;
    const int kOff = CEMB + h * 64;
    const unsigned short* Vhead = VtG + (size_t)bh * 64 * TSEQ;

    // Q fragments for both tiles
    bf16x8 qfA[2], qfB[2];
    {
        const size_t rA = rowBase + (size_t)qtA * 64 + 16 * w + lq;
        const size_t rB = rowBase + (size_t)qtB * 64 + 16 * w + lq;
#pragma unroll
        for (int dt = 0; dt < 2; ++dt) {
            qfA[dt] = *reinterpret_cast<const bf16x8*>(&qkvB[rA * 2304 + h * 64 + 32 * dt + 8 * g]);
            qfB[dt] = *reinterpret_cast<const bf16x8*>(&qkvB[rB * 2304 + h * 64 + 32 * dt + 8 * g]);
        }
    }

    f32x4 oA[4], oB[4];
    float mA[4], lA[4], mB[4], lB[4];
#pragma unroll
    for (int r = 0; r < 4; ++r) {
        mA[r] = -1e30f; lA[r] = 0.f; mB[r] = -1e30f; lB[r] = 0.f;
    }
#pragma unroll
    for (int dt = 0; dt < 4; ++dt) {
        oA[dt] = (f32x4){0.f, 0.f, 0.f, 0.f};
        oB[dt] = (f32x4){0.f, 0.f, 0.f, 0.f};
    }

    char* Pw = Pl + w * 2048;

    // prologue: stage kt=0 into buffer 0 (async, drained by first barrier)
#pragma unroll
    for (int it = 0; it < 2; ++it) {
        const int dbase = it * 256 + w * 64;
        const int d = dbase + lane;
        const int r = d >> 3;
        const int s = (d & 7) ^ (r & 7);
        async_cp16(Kl[0] + dbase * 16, qkvB + (rowBase + r) * 2304 + kOff + s * 8);
        async_cp16(Vl[0] + dbase * 16, Vhead + (size_t)r * TSEQ + s * 8);
    }

    for (int kt = 0; kt <= qtB; ++kt) {
        const int cur = kt & 1;
        __syncthreads();   // drains staging for kt; also fences buf[cur^1] reuse

        // prefetch kt+1 into the other buffer; latency hides under compute below
        if (kt < qtB) {
            const int kn = (kt + 1) * 64;
#pragma unroll
            for (int it = 0; it < 2; ++it) {
                const int dbase = it * 256 + w * 64;
                const int d = dbase + lane;
                const int r = d >> 3;
                const int s = (d & 7) ^ (r & 7);
                async_cp16(Kl[cur ^ 1] + dbase * 16,
                           qkvB + (rowBase + kn + r) * 2304 + kOff + s * 8);
                async_cp16(Vl[cur ^ 1] + dbase * 16,
                           Vhead + (size_t)r * TSEQ + kn + s * 8);
            }
        }

        const char* Kb = Kl[cur];
        const char* Vb = Vl[cur];

        if (kt <= qtA) PROCESS_TILE(qfA, mA, lA, oA, (kt == qtA));
        PROCESS_TILE(qfB, mB, lB, oB, (kt == qtB));
    }

    // write both tiles' outputs (bf16)
#pragma unroll
    for (int r = 0; r < 4; ++r) {
        const float invA = 1.f / lA[r];
        const float invB = 1.f / lB[r];
        const size_t rowA = rowBase + (size_t)qtA * 64 + 16 * w + 4 * g + r;
        const size_t rowB = rowBase + (size_t)qtB * 64 + 16 * w + 4 * g + r;
#pragma unroll
        for (int dt = 0; dt < 4; ++dt) {
            Yb[rowA * CEMB + h * 64 + 16 * dt + lq] = (unsigned short)f2bf(oA[dt][r] * invA);
            Yb[rowB * CEMB + h * 64 + 16 * dt + lq] = (unsigned short)f2bf(oB[dt][r] * invB);
        }
    }
}

extern "C" void kernel_launch(void* const* d_in, const int* in_sizes, int n_in,
                              void* d_out, int out_size, void* d_ws, size_t ws_size,
                              hipStream_t stream)
{
    const float* x      = (const float*)d_in[0];
    const float* w_attn = (const float*)d_in[1];
    const float* b_attn = (const float*)d_in[2];
    const float* w_proj = (const float*)d_in[3];
    const float* b_proj = (const float*)d_in[4];
    float* out = (float*)d_out;

    const int M = 2 * TSEQ;  // 8192
    char* ws = (char*)d_ws;
    unsigned short* qkvB = (unsigned short*)ws;                   // 37,748,736 B
    unsigned short* VtG  = (unsigned short*)(ws + 37748736);      // 12,582,912 B
    unsigned short* xYb  = (unsigned short*)(ws + 50331648);      // 12,582,912 B (xB, then Yb)
    unsigned short* wT   = (unsigned short*)(ws + 62914560);      //  3,538,944 B
    unsigned short* wpT  = (unsigned short*)(ws + 66453504);      //  1,179,648 B

    cvt_bf16<<<dim3((M * CEMB) / 8 / 256), 256, 0, stream>>>(x, xYb, (M * CEMB) / 8);
    wtrans<<<dim3(3 * CEMB / 64, CEMB / 64), 256, 0, stream>>>(w_attn, wT, CEMB, 3 * CEMB);
    wtrans<<<dim3(CEMB / 64, CEMB / 64), 256, 0, stream>>>(w_proj, wpT, CEMB, CEMB);

    gemm_mfma<1, 1><<<dim3(3 * CEMB / 128, M / 128), 256, 0, stream>>>(
        xYb, wT, b_attn, qkvB, M, 3 * CEMB, CEMB);

    vtrans<<<dim3(TSEQ / 64, 2 * NHEAD), 256, 0, stream>>>(qkvB, VtG);

    // balanced pairs: grid.x = 32 (tiles i and 63-i per block)
    attn_mfma3<<<dim3(TSEQ / 128, 2 * NHEAD), 256, 0, stream>>>(qkvB, VtG, xYb);

    gemm_mfma<0, 0><<<dim3(CEMB / 128, M / 128), 256, 0, stream>>>(
        xYb, wpT, b_proj, out, M, CEMB, CEMB);
}

// Round 6
// 257.768 us; speedup vs baseline: 1.8490x; 1.2740x over previous
//
#include <hip/hip_runtime.h>

#define TSEQ 4096
#define CEMB 768
#define NHEAD 12

using bf16x8 = __attribute__((ext_vector_type(8))) short;
using f32x4  = __attribute__((ext_vector_type(4))) float;

#if __has_builtin(__builtin_amdgcn_exp2f)
#define EXP2(x) __builtin_amdgcn_exp2f(x)
#else
#define EXP2(x) exp2f(x)
#endif

__device__ __forceinline__ unsigned int f2bf(float f) {
    unsigned int u = __float_as_uint(f);
    return (u + 0x7fffu + ((u >> 16) & 1u)) >> 16;   // RNE
}
__device__ __forceinline__ unsigned int f2bf_fast(float f) {
    return (__float_as_uint(f) + 0x8000u) >> 16;     // ~RNE, <=1ulp diff
}
__device__ __forceinline__ void async_cp16(void* lds, const void* g) {
    __builtin_amdgcn_global_load_lds(
        (const __attribute__((address_space(1))) void*)g,
        (__attribute__((address_space(3))) void*)lds, 16, 0, 0);
}
__device__ __forceinline__ float warp_max16(float v) {
    v = fmaxf(v, __shfl_xor(v, 1));
    v = fmaxf(v, __shfl_xor(v, 2));
    v = fmaxf(v, __shfl_xor(v, 4));
    v = fmaxf(v, __shfl_xor(v, 8));
    return v;
}
__device__ __forceinline__ float warp_sum16(float v) {
    v += __shfl_xor(v, 1);
    v += __shfl_xor(v, 2);
    v += __shfl_xor(v, 4);
    v += __shfl_xor(v, 8);
    return v;
}

// ---------------- x fp32 -> bf16 ----------------
__global__ __launch_bounds__(256) void cvt_bf16(
    const float* __restrict__ X, unsigned short* __restrict__ Xb, int n8)
{
    int i = blockIdx.x * 256 + threadIdx.x;
    if (i >= n8) return;
    float4 a = *reinterpret_cast<const float4*>(&X[(size_t)i * 8]);
    float4 b = *reinterpret_cast<const float4*>(&X[(size_t)i * 8 + 4]);
    uint4 o;
    o.x = f2bf(a.x) | (f2bf(a.y) << 16);
    o.y = f2bf(a.z) | (f2bf(a.w) << 16);
    o.z = f2bf(b.x) | (f2bf(b.y) << 16);
    o.w = f2bf(b.z) | (f2bf(b.w) << 16);
    *reinterpret_cast<uint4*>(&Xb[(size_t)i * 8]) = o;
}

// ---------------- W fp32 [K][N] -> bf16 [N][K] ----------------
__global__ __launch_bounds__(256) void wtrans(
    const float* __restrict__ W, unsigned short* __restrict__ WT, int K, int N)
{
    __shared__ unsigned short tile[64][72];
    const int k0 = blockIdx.y * 64, n0 = blockIdx.x * 64;
    const int tid = threadIdx.x;
#pragma unroll
    for (int it = 0; it < 4; ++it) {
        int f = tid + it * 256;
        int r = f >> 4, c4 = f & 15;
        float4 v = *reinterpret_cast<const float4*>(&W[(size_t)(k0 + r) * N + n0 + c4 * 4]);
        tile[r][c4 * 4 + 0] = (unsigned short)f2bf(v.x);
        tile[r][c4 * 4 + 1] = (unsigned short)f2bf(v.y);
        tile[r][c4 * 4 + 2] = (unsigned short)f2bf(v.z);
        tile[r][c4 * 4 + 3] = (unsigned short)f2bf(v.w);
    }
    __syncthreads();
#pragma unroll
    for (int it = 0; it < 2; ++it) {
        int f = tid + it * 256;
        int rn = f >> 3, c8 = f & 7;
        unsigned short tmp[8];
#pragma unroll
        for (int j = 0; j < 8; ++j) tmp[j] = tile[c8 * 8 + j][rn];
        *reinterpret_cast<uint4*>(&WT[(size_t)(n0 + rn) * K + k0 + c8 * 8]) =
            *reinterpret_cast<uint4*>(tmp);
    }
}

// ---------------- bf16 MFMA GEMM: C[m][n] = A[m][k] * BT[n][k] + bias ----------------
template<int BF16OUT, int QSCALE>
__global__ __launch_bounds__(256) void gemm_mfma(
    const unsigned short* __restrict__ A,
    const unsigned short* __restrict__ BT,
    const float* __restrict__ bias,
    void* __restrict__ Cv,
    int M, int N, int K)
{
    __shared__ __align__(16) unsigned short As[128 * 64];
    __shared__ __align__(16) unsigned short Bs[128 * 64];

    const int nwg = gridDim.x * gridDim.y;
    const int id = blockIdx.y * gridDim.x + blockIdx.x;
    const int qx = nwg >> 3;
    const int swz = (id & 7) * qx + (id >> 3);
    const int nb = N >> 7;
    const int m0 = (swz / nb) * 128, n0 = (swz % nb) * 128;

    const int tid = threadIdx.x;
    const int w = tid >> 6, lane = tid & 63;
    const int wr = w >> 1, wc = w & 1;
    const int lq = lane & 15, g = lane >> 4;
    const int wrOff = wr * 64, wcOff = wc * 64;

    f32x4 acc[4][4];
#pragma unroll
    for (int i = 0; i < 4; ++i)
#pragma unroll
        for (int j = 0; j < 4; ++j) acc[i][j] = (f32x4){0.f, 0.f, 0.f, 0.f};

    for (int k0 = 0; k0 < K; k0 += 64) {
#pragma unroll
        for (int it = 0; it < 4; ++it) {
            const int dbase = it * 256 + w * 64;
            const int d = dbase + lane;
            const int r = d >> 3;
            const int s = (d & 7) ^ (r & 7);
            async_cp16((char*)As + dbase * 16, A + (size_t)(m0 + r) * K + k0 + s * 8);
            async_cp16((char*)Bs + dbase * 16, BT + (size_t)(n0 + r) * K + k0 + s * 8);
        }
        __syncthreads();

#pragma unroll
        for (int kk = 0; kk < 2; ++kk) {
            bf16x8 af[4], bfr[4];
#pragma unroll
            for (int i = 0; i < 4; ++i) {
                const int ra = wrOff + i * 16 + lq;
                af[i] = *reinterpret_cast<const bf16x8*>(
                    (char*)As + ra * 128 + (((kk * 4 + g) ^ (ra & 7)) << 4));
                const int rb = wcOff + i * 16 + lq;
                bfr[i] = *reinterpret_cast<const bf16x8*>(
                    (char*)Bs + rb * 128 + (((kk * 4 + g) ^ (rb & 7)) << 4));
            }
#pragma unroll
            for (int i = 0; i < 4; ++i)
#pragma unroll
                for (int j = 0; j < 4; ++j)
                    acc[i][j] = __builtin_amdgcn_mfma_f32_16x16x32_bf16(
                        af[i], bfr[j], acc[i][j], 0, 0, 0);
        }
        __syncthreads();
    }

#pragma unroll
    for (int i = 0; i < 4; ++i)
#pragma unroll
        for (int j = 0; j < 4; ++j) {
            const int col = n0 + wcOff + j * 16 + lq;
            const float bv = bias[col];
            // q gets 1/8 (attn scale) * log2(e) (exp2-domain softmax) folded in
            const float scl = (QSCALE && col < CEMB) ? 0.18033688011112042f : 1.0f;
#pragma unroll
            for (int rg = 0; rg < 4; ++rg) {
                const int row = m0 + wrOff + i * 16 + g * 4 + rg;
                const float v = (acc[i][j][rg] + bv) * scl;
                if (BF16OUT)
                    ((unsigned short*)Cv)[(size_t)row * N + col] = (unsigned short)f2bf(v);
                else
                    ((float*)Cv)[(size_t)row * N + col] = v;
            }
        }
}

// ---------------- V transpose: qkv bf16 v-slice -> Vt [bh][64 d][4096 t] ----------------
__global__ __launch_bounds__(256) void vtrans(
    const unsigned short* __restrict__ qkvB, unsigned short* __restrict__ VtG)
{
    __shared__ unsigned short tile[64][66];
    const int t0 = blockIdx.x * 64;
    const int bh = blockIdx.y;
    const int b = bh / NHEAD, h = bh % NHEAD;
    const size_t rowBase = (size_t)b * TSEQ;
    const int tid = threadIdx.x;

#pragma unroll
    for (int it = 0; it < 2; ++it) {
        int f = tid + 256 * it;
        int r = f >> 3, s = f & 7;
        unsigned short tmp[8];
        *reinterpret_cast<uint4*>(tmp) = *reinterpret_cast<const uint4*>(
            &qkvB[(rowBase + t0 + r) * 2304 + 2 * CEMB + h * 64 + s * 8]);
#pragma unroll
        for (int j = 0; j < 8; ++j) tile[r][s * 8 + j] = tmp[j];
    }
    __syncthreads();
#pragma unroll
    for (int it = 0; it < 2; ++it) {
        int f = tid + 256 * it;
        int d = f >> 3, c = f & 7;
        unsigned short tmp[8];
#pragma unroll
        for (int j = 0; j < 8; ++j) tmp[j] = tile[c * 8 + j][d];
        *reinterpret_cast<uint4*>(&VtG[(size_t)bh * 64 * TSEQ + (size_t)d * TSEQ + t0 + c * 8]) =
            *reinterpret_cast<uint4*>(tmp);
    }
}

// ---- per-tile pieces (layouts identical to the numerically-verified r3/r5 kernel) ----
#define QK_TILE(SFR, QF)                                                              \
{                                                                                     \
    _Pragma("unroll")                                                                 \
    for (int c = 0; c < 4; ++c) {                                                     \
        const int kvr = 16 * c + lq;                                                  \
        const int xr = lq & 7;                                                        \
        bf16x8 k0 = *reinterpret_cast<const bf16x8*>(Kb + kvr * 128 + ((g ^ xr) << 4));       \
        bf16x8 k1 = *reinterpret_cast<const bf16x8*>(Kb + kvr * 128 + (((4 + g) ^ xr) << 4)); \
        f32x4 a0 = (f32x4){0.f, 0.f, 0.f, 0.f};                                       \
        a0 = __builtin_amdgcn_mfma_f32_16x16x32_bf16(QF[0], k0, a0, 0, 0, 0);         \
        a0 = __builtin_amdgcn_mfma_f32_16x16x32_bf16(QF[1], k1, a0, 0, 0, 0);         \
        SFR[c] = a0;                                                                  \
    }                                                                                 \
}

#define MASK_TILE(SFR)                                                                \
{                                                                                     \
    const int qp = 16 * w + 4 * g;                                                    \
    _Pragma("unroll")                                                                 \
    for (int c = 0; c < 4; ++c) {                                                     \
        const int kp = 16 * c + lq;                                                   \
        _Pragma("unroll")                                                             \
        for (int r = 0; r < 4; ++r)                                                   \
            if (kp > qp + r) SFR[c][r] = -1e30f;                                      \
    }                                                                                 \
}

#define SM_TILE(SFR, MM, LL, OO)                                                      \
{                                                                                     \
    _Pragma("unroll")                                                                 \
    for (int r = 0; r < 4; ++r) {                                                     \
        float mx = fmaxf(fmaxf(SFR[0][r], SFR[1][r]), fmaxf(SFR[2][r], SFR[3][r]));   \
        mx = warp_max16(mx);                                                          \
        const float mnew = fmaxf(MM[r], mx);                                          \
        const float al = EXP2(MM[r] - mnew);                                          \
        float rs = 0.f;                                                               \
        _Pragma("unroll")                                                             \
        for (int c = 0; c < 4; ++c) {                                                 \
            const float p = EXP2(SFR[c][r] - mnew);                                   \
            SFR[c][r] = p;                                                            \
            rs += p;                                                                  \
        }                                                                             \
        rs = warp_sum16(rs);                                                          \
        LL[r] = al * LL[r] + rs;                                                      \
        MM[r] = mnew;                                                                 \
        _Pragma("unroll")                                                             \
        for (int dt = 0; dt < 4; ++dt) OO[dt][r] *= al;                               \
    }                                                                                 \
}

#define PW_TILE(SFR, PWP)                                                             \
{                                                                                     \
    _Pragma("unroll")                                                                 \
    for (int c = 0; c < 4; ++c) {                                                     \
        const int kp = 16 * c + lq;                                                   \
        _Pragma("unroll")                                                             \
        for (int r = 0; r < 4; ++r) {                                                 \
            const int qp = 4 * g + r;                                                 \
            const int byt = qp * 128 + (((kp >> 3) ^ (qp & 7)) << 4) + (kp & 7) * 2;  \
            *reinterpret_cast<unsigned short*>(PWP + byt) =                           \
                (unsigned short)f2bf_fast(SFR[c][r]);                                 \
        }                                                                             \
    }                                                                                 \
}

#define PV_TILE(OO, PWP)                                                              \
{                                                                                     \
    _Pragma("unroll")                                                                 \
    for (int ktile = 0; ktile < 2; ++ktile) {                                         \
        bf16x8 pf = *reinterpret_cast<const bf16x8*>(                                 \
            PWP + lq * 128 + (((4 * ktile + g) ^ (lq & 7)) << 4));                    \
        _Pragma("unroll")                                                             \
        for (int dt = 0; dt < 4; ++dt) {                                              \
            const int d = 16 * dt + lq;                                               \
            bf16x8 vf = *reinterpret_cast<const bf16x8*>(                             \
                Vb + d * 128 + (((4 * ktile + g) ^ (d & 7)) << 4));                   \
            OO[dt] = __builtin_amdgcn_mfma_f32_16x16x32_bf16(pf, vf, OO[dt], 0, 0, 0);\
        }                                                                             \
    }                                                                                 \
}

#define STAGE_KV(KT, BUF)                                                             \
{                                                                                     \
    const int kn = (KT) * 64;                                                         \
    _Pragma("unroll")                                                                 \
    for (int it = 0; it < 2; ++it) {                                                  \
        const int dbase = it * 256 + w * 64;                                          \
        const int d = dbase + lane;                                                   \
        const int r = d >> 3;                                                         \
        const int s = (d & 7) ^ (r & 7);                                              \
        async_cp16(Kl[BUF] + dbase * 16, qkvB + (rowBase + kn + r) * 2304 + kOff + s * 8); \
        async_cp16(Vl[BUF] + dbase * 16, Vhead + (size_t)r * TSEQ + kn + s * 8);      \
    }                                                                                 \
}

// ---------------- MFMA flash attention v4: paired q-tiles, staggered dual-chain ----------------
// grid (T/128, B*H), block 256 = 4 waves. Block i handles q-tiles i and 63-i.
__global__ __launch_bounds__(256, 3) void attn_mfma4(
    const unsigned short* __restrict__ qkvB,   // bf16 [8192][2304], q pre-scaled 0.125*log2e
    const unsigned short* __restrict__ VtG,    // bf16 [24][64][4096]
    unsigned short* __restrict__ Yb)           // bf16 [8192][768]
{
    __shared__ __align__(16) char Kl[2][8192];   // [kv 64][d 64], 16B-chunk XOR swizzle
    __shared__ __align__(16) char Vl[2][8192];   // [d 64][kv 64], swizzled
    __shared__ __align__(16) char PlA[8192];     // 4 waves x [q 16][kv 64], swizzled
    __shared__ __align__(16) char PlB[8192];

    const int NT = TSEQ / 64;
    const int qtA = blockIdx.x;                  // 0..31
    const int qtB = NT - 1 - qtA;                // 63..32
    const int bh = blockIdx.y;
    const int b = bh / NHEAD, h = bh % NHEAD;
    const int tid = threadIdx.x;
    const int w = tid >> 6, lane = tid & 63;
    const int g = lane >> 4, lq = lane & 15;

    const size_t rowBase = (size_t)b * TSEQ;
    const int kOff = CEMB + h * 64;
    const unsigned short* Vhead = VtG + (size_t)bh * 64 * TSEQ;

    bf16x8 qfA[2], qfB[2];
    {
        const size_t rA = rowBase + (size_t)qtA * 64 + 16 * w + lq;
        const size_t rB = rowBase + (size_t)qtB * 64 + 16 * w + lq;
#pragma unroll
        for (int dt = 0; dt < 2; ++dt) {
            qfA[dt] = *reinterpret_cast<const bf16x8*>(&qkvB[rA * 2304 + h * 64 + 32 * dt + 8 * g]);
            qfB[dt] = *reinterpret_cast<const bf16x8*>(&qkvB[rB * 2304 + h * 64 + 32 * dt + 8 * g]);
        }
    }

    f32x4 oA[4], oB[4];
    float mA[4], lA[4], mB[4], lB[4];
#pragma unroll
    for (int r = 0; r < 4; ++r) {
        mA[r] = -1e30f; lA[r] = 0.f; mB[r] = -1e30f; lB[r] = 0.f;
    }
#pragma unroll
    for (int dt = 0; dt < 4; ++dt) {
        oA[dt] = (f32x4){0.f, 0.f, 0.f, 0.f};
        oB[dt] = (f32x4){0.f, 0.f, 0.f, 0.f};
    }

    char* PwA = PlA + w * 2048;
    char* PwB = PlB + w * 2048;

    STAGE_KV(0, 0);

    // ---- phase 1: kt = 0..qtA — both tiles active, staggered dual chains ----
    for (int kt = 0; kt <= qtA; ++kt) {
        const int cur = kt & 1;
        __syncthreads();
        STAGE_KV(kt + 1, cur ^ 1);           // kt+1 <= qtA+1 <= qtB, always valid
        const char* Kb = Kl[cur];
        const char* Vb = Vl[cur];

        f32x4 sfrA[4], sfrB[4];
        QK_TILE(sfrA, qfA);
        QK_TILE(sfrB, qfB);
        if (kt == qtA) MASK_TILE(sfrA);
        SM_TILE(sfrA, mA, lA, oA);
        SM_TILE(sfrB, mB, lB, oB);
        PW_TILE(sfrA, PwA);
        PW_TILE(sfrB, PwB);
        PV_TILE(oA, PwA);
        PV_TILE(oB, PwB);
    }

    // ---- phase 2: kt = qtA+1..qtB — only tile B ----
    for (int kt = qtA + 1; kt <= qtB; ++kt) {
        const int cur = kt & 1;
        __syncthreads();
        if (kt < qtB) STAGE_KV(kt + 1, cur ^ 1);
        const char* Kb = Kl[cur];
        const char* Vb = Vl[cur];

        f32x4 sfrB[4];
        QK_TILE(sfrB, qfB);
        if (kt == qtB) MASK_TILE(sfrB);
        SM_TILE(sfrB, mB, lB, oB);
        PW_TILE(sfrB, PwB);
        PV_TILE(oB, PwB);
    }

    // ---- outputs ----
#pragma unroll
    for (int r = 0; r < 4; ++r) {
        const float invA = 1.f / lA[r];
        const float invB = 1.f / lB[r];
        const size_t rowA = rowBase + (size_t)qtA * 64 + 16 * w + 4 * g + r;
        const size_t rowB = rowBase + (size_t)qtB * 64 + 16 * w + 4 * g + r;
#pragma unroll
        for (int dt = 0; dt < 4; ++dt) {
            Yb[rowA * CEMB + h * 64 + 16 * dt + lq] = (unsigned short)f2bf_fast(oA[dt][r] * invA);
            Yb[rowB * CEMB + h * 64 + 16 * dt + lq] = (unsigned short)f2bf_fast(oB[dt][r] * invB);
        }
    }
}

extern "C" void kernel_launch(void* const* d_in, const int* in_sizes, int n_in,
                              void* d_out, int out_size, void* d_ws, size_t ws_size,
                              hipStream_t stream)
{
    const float* x      = (const float*)d_in[0];
    const float* w_attn = (const float*)d_in[1];
    const float* b_attn = (const float*)d_in[2];
    const float* w_proj = (const float*)d_in[3];
    const float* b_proj = (const float*)d_in[4];
    float* out = (float*)d_out;

    const int M = 2 * TSEQ;  // 8192
    char* ws = (char*)d_ws;
    unsigned short* qkvB = (unsigned short*)ws;                   // 37,748,736 B
    unsigned short* VtG  = (unsigned short*)(ws + 37748736);      // 12,582,912 B
    unsigned short* xYb  = (unsigned short*)(ws + 50331648);      // 12,582,912 B (xB, then Yb)
    unsigned short* wT   = (unsigned short*)(ws + 62914560);      //  3,538,944 B
    unsigned short* wpT  = (unsigned short*)(ws + 66453504);      //  1,179,648 B

    cvt_bf16<<<dim3((M * CEMB) / 8 / 256), 256, 0, stream>>>(x, xYb, (M * CEMB) / 8);
    wtrans<<<dim3(3 * CEMB / 64, CEMB / 64), 256, 0, stream>>>(w_attn, wT, CEMB, 3 * CEMB);
    wtrans<<<dim3(CEMB / 64, CEMB / 64), 256, 0, stream>>>(w_proj, wpT, CEMB, CEMB);

    gemm_mfma<1, 1><<<dim3(3 * CEMB / 128, M / 128), 256, 0, stream>>>(
        xYb, wT, b_attn, qkvB, M, 3 * CEMB, CEMB);

    vtrans<<<dim3(TSEQ / 64, 2 * NHEAD), 256, 0, stream>>>(qkvB, VtG);

    attn_mfma4<<<dim3(TSEQ / 128, 2 * NHEAD), 256, 0, stream>>>(qkvB, VtG, xYb);

    gemm_mfma<0, 0><<<dim3(CEMB / 128, M / 128), 256, 0, stream>>>(
        xYb, wpT, b_proj, out, M, CEMB, CEMB);
}